// Round 1
// 123.383 us; speedup vs baseline: 1.1856x; 1.1856x over previous
//
#include <hip/hip_runtime.h>

typedef float f2 __attribute__((ext_vector_type(2)));

#define HW 64
#define LH 150
#define LQ 10

#define X36R (36*64)     // staged X rows per channel: global [base-2 .. base+33]
#define R34  (34*64)     // r rows: global [base-1 .. base+32]
#define SMEM_TOT (2*X36R + R34 + 32)

// Cross-block halo slots: [dir 2][parity 2][img 128][lane 64] of {seq:32|val:32}.
// Device global so we don't depend on ws_size; host memsets it each launch.
__device__ unsigned long long g_halo[2*2*128*64];

// Full-wave lane shifts; bound_ctrl zero-fill == SAME padding at cols 0/63.
__device__ __forceinline__ float dpp_wshr1(float x) {   // lane i <- lane i-1
    return __builtin_bit_cast(float, __builtin_amdgcn_update_dpp(
        0, __builtin_bit_cast(int, x), 0x138, 0xF, 0xF, true));
}
__device__ __forceinline__ float dpp_wshl1(float x) {   // lane i <- lane i+1
    return __builtin_bit_cast(float, __builtin_amdgcn_update_dpp(
        0, __builtin_bit_cast(int, x), 0x130, 0xF, 0xF, true));
}
__device__ __forceinline__ f2 dpp2_shr(f2 v) { return (f2){dpp_wshr1(v.x), dpp_wshr1(v.y)}; }
__device__ __forceinline__ f2 dpp2_shl(f2 v) { return (f2){dpp_wshl1(v.x), dpp_wshl1(v.y)}; }

// VOP3P packed fp32 FMA, weight broadcast from one word of an SGPR pair.
__device__ __forceinline__ f2 pk_fma_b0(f2 a, f2 wpair, f2 c) {
    f2 d;
    asm("v_pk_fma_f32 %0, %1, %2, %3 op_sel_hi:[1,0,1]"
        : "=v"(d) : "v"(a), "s"(wpair), "v"(c));
    return d;
}
__device__ __forceinline__ f2 pk_fma_b1(f2 a, f2 wpair, f2 c) {
    f2 d;
    asm("v_pk_fma_f32 %0, %1, %2, %3 op_sel:[0,1,0]"
        : "=v"(d) : "v"(a), "s"(wpair), "v"(c));
    return d;
}

// 256 blocks = 2 half-image blocks per image (rows 0..31 / 32..63), 1024 threads
// = 16 waves; wave w owns rows base+2w, base+2w+1 (one f2 pair). lane = column.
// Horizontal halos via wave DPP; intra-block vertical halos via parity LDS slots
// with a raw lgkmcnt-only barrier; the ONE cross-block boundary row per direction
// goes through L3 as an 8-byte {seq|value} relaxed agent-scope atomic per lane
// (self-synchronizing, no flags/fences), parity double-buffered.
__global__ __launch_bounds__(1024)
void vin_main(const float* __restrict__ X,
              const float* __restrict__ h_w,
              const float* __restrict__ h_b,
              const float* __restrict__ r_w,
              const float* __restrict__ q_w,
              const float* __restrict__ wgt,
              const int* __restrict__ kptr,
              float* __restrict__ out) {
    __shared__ float smem[SMEM_TOT];   // X0 | X1 | r | weff(32)
    float* sR  = smem + 2*X36R;
    float* sWE = smem + 2*X36R + R34;
    // halo slots alias dead X region after prologue: [2][17][64] each
    float* sHB = smem;                 // bottom rows; wave w writes [p][w+1]; pad [p][0]=0
    float* sHT = smem + 2176;          // top rows;    wave w writes [p][w];   pad [p][16]=0

    const int bid = blockIdx.x;
    const int img = bid & 127, half = bid >> 7;
    const int base = half << 5;        // 0 or 32
    const int tid = threadIdx.x;
    const int w = tid >> 6, l = tid & 63;

    for (int i = tid; i < SMEM_TOT; i += 1024) smem[i] = 0.f;
    __syncthreads();

    // ---- fused weff: wave w computes outputs j = w, w+16 (j<19) ----
    #pragma unroll
    for (int i = 0; i < 2; ++i) {
        int j = w + 16*i;
        if (j < 19) {
            float s = 0.f;
            #pragma unroll
            for (int u = 0; u < 3; ++u) {
                int t = l + 64*u;
                if (t < LH) {
                    float src = (j < 18) ? h_w[t*18 + j] : h_b[t];
                    s = fmaf(r_w[t], src, s);
                }
            }
            #pragma unroll
            for (int off = 32; off >= 1; off >>= 1)
                s += __shfl_xor(s, off);
            if (l == 0) sWE[j] = s;
        }
    }

    // ---- stage X global rows [base-2 .. base+33] clipped to [0,63] ----
    // LDS X row = globalRow - (base-2); out-of-image rows stay zero.
    const float* Xb = X + (size_t)img * 2 * HW * HW;
    const int r0v    = half ? 30 : 0;   // first valid staged global row
    const int ldsOff = half ? 0  : 2;   // its LDS row
    for (int i = tid; i < 2*34*16; i += 1024) {
        int ch = i / 544, j = i - ch*544;
        int row = j >> 4, c = j & 15;
        float4 v = *(const float4*)(Xb + ((size_t)ch*HW + (r0v + row))*HW + c*4);
        *(float4*)(smem + ch*X36R + (ldsOff + row)*64 + c*4) = v;
    }
    __syncthreads();

    // ---- r rows: LDS r row j (0..33) == global row base-1+j ----
    float wE[19];
    #pragma unroll
    for (int i = 0; i < 19; ++i) wE[i] = sWE[i];
    for (int j = w; j < 34; j += 16) {
        int gj = base - 1 + j;
        if (gj >= 0 && gj < 64) {       // rows -1 / 64 stay zero (SAME pad)
            float acc = wE[18];
            #pragma unroll
            for (int ch = 0; ch < 2; ++ch)
                #pragma unroll
                for (int dy = 0; dy < 3; ++dy) {
                    float xc = smem[ch*X36R + (j + dy)*64 + l];
                    float xl = dpp_wshr1(xc);
                    float xr = dpp_wshl1(xc);
                    acc = fmaf(xl, wE[ch*9 + dy*3 + 0], acc);
                    acc = fmaf(xc, wE[ch*9 + dy*3 + 1], acc);
                    acc = fmaf(xr, wE[ch*9 + dy*3 + 2], acc);
                }
            sR[j*64 + l] = acc;
        }
    }
    __syncthreads();   // X regions dead after this -> halo slots may alias

    // ---- qr[a] = conv3x3(r, q_w[a]) for my 2 rows; v0 = max_a qr ----
    f2 qr[LQ];
    f2 vc;
    {
        float rc[4], rl[4], rr2[4];
        #pragma unroll
        for (int kk = 0; kk < 4; ++kk) {
            rc[kk]  = sR[(2*w + kk)*64 + l];   // r global rows base+2w-1 .. +2
            rl[kk]  = dpp_wshr1(rc[kk]);
            rr2[kk] = dpp_wshl1(rc[kk]);
        }
        float vcur[2];
        #pragma unroll
        for (int a = 0; a < LQ; ++a) {
            float qa[9];
            #pragma unroll
            for (int i = 0; i < 9; ++i) qa[i] = q_w[a*9 + i];
            float acc[2];
            #pragma unroll
            for (int i = 0; i < 2; ++i) {
                float s = 0.f;
                #pragma unroll
                for (int dy = 0; dy < 3; ++dy) {
                    s = fmaf(rl[i+dy],  qa[dy*3 + 0], s);
                    s = fmaf(rc[i+dy],  qa[dy*3 + 1], s);
                    s = fmaf(rr2[i+dy], qa[dy*3 + 2], s);
                }
                acc[i] = s;
                vcur[i] = a ? fmaxf(vcur[i], s) : s;
            }
            qr[a] = (f2){acc[0], acc[1]};
        }
        vc = (f2){vcur[0], vcur[1]};
    }
    // zero the 4 halo pad rows (alias region; X dead since last barrier)
    if (tid < 256) {
        int p = tid >> 7, hh = (tid >> 6) & 1, ll = tid & 63;
        if (hh == 0) sHB[p*1088 + 0*64  + ll] = 0.f;
        else         sHT[p*1088 + 16*64 + ll] = 0.f;
    }

    // ---- weights as 45 packed pairs (wave-uniform -> SGPRs) ----
    f2 wv2[LQ][5];
    #pragma unroll
    for (int a = 0; a < LQ; ++a) {
        #pragma unroll
        for (int p = 0; p < 4; ++p)
            wv2[a][p] = (f2){wgt[a*9 + 2*p], wgt[a*9 + 2*p + 1]};
        wv2[a][4] = (f2){wgt[a*9 + 8], 0.f};
    }

    // ---- cross-block halo wiring ----
    // dir0 (down): half0 row31 (w15, vc.y) -> half1 w0's ht
    // dir1 (up):   half1 row32 (w0,  vc.x) -> half0 w15's hb
    const bool downSend = (half == 0) && (w == 15);   // also receives up
    const bool upSend   = (half == 1) && (w == 0);    // also receives down
    unsigned long long* dn = g_halo;                  // [2][128][64]
    unsigned long long* up = g_halo + 2*128*64;

    // ---- value iteration: v <- max_a (qr[a] + conv3x3(v, w[a])) ----
    const int km1 = kptr[0] - 1;
    const int wrB = (w+1)*64 + l;
    const int wrT = w*64 + l;
    for (int t = 0; t < km1; ++t) {
        const int p = (t & 1);
        // fire-and-forget remote sends (not drained by the raw barrier below)
        if (downSend) {
            float vy = vc.y;
            unsigned long long u = ((unsigned long long)(unsigned)(t + 1) << 32)
                                 | (unsigned long long)__builtin_bit_cast(unsigned, vy);
            __hip_atomic_store(&dn[(p*128 + img)*64 + l], u,
                               __ATOMIC_RELAXED, __HIP_MEMORY_SCOPE_AGENT);
        }
        if (upSend) {
            float vx = vc.x;
            unsigned long long u = ((unsigned long long)(unsigned)(t + 1) << 32)
                                 | (unsigned long long)__builtin_bit_cast(unsigned, vx);
            __hip_atomic_store(&up[(p*128 + img)*64 + l], u,
                               __ATOMIC_RELAXED, __HIP_MEMORY_SCOPE_AGENT);
        }
        sHB[p*1088 + wrB] = vc.y;     // my row base+2w+1
        sHT[p*1088 + wrT] = vc.x;     // my row base+2w
        // loop has only LDS dependencies -> lgkmcnt-only drain (keep sends in flight)
        asm volatile("s_waitcnt lgkmcnt(0)" ::: "memory");
        __builtin_amdgcn_s_barrier();
        float ht = sHB[p*1088 + wrT]; // row base+2w-1 (zero for w==0)
        float hb = sHT[p*1088 + wrB]; // row base+2w+2 (zero for w==15)
        if (upSend) {                 // half1 w0: ht = partner's row 31
            unsigned long long u;
            do {
                u = __hip_atomic_load(&dn[(p*128 + img)*64 + l],
                                      __ATOMIC_RELAXED, __HIP_MEMORY_SCOPE_AGENT);
            } while ((unsigned)(u >> 32) != (unsigned)(t + 1));
            ht = __builtin_bit_cast(float, (unsigned)u);
        }
        if (downSend) {               // half0 w15: hb = partner's row 32
            unsigned long long u;
            do {
                u = __hip_atomic_load(&up[(p*128 + img)*64 + l],
                                      __ATOMIC_RELAXED, __HIP_MEMORY_SCOPE_AGENT);
            } while ((unsigned)(u >> 32) != (unsigned)(t + 1));
            hb = __builtin_bit_cast(float, (unsigned)u);
        }

        // vv = [ht, v0, v1, hb]; aligned pairs P0/P1; odd pair = vc
        f2 P0 = (f2){ht,   vc.x};
        f2 P1 = (f2){vc.y, hb};
        f2 P0L = dpp2_shr(P0), P0R = dpp2_shl(P0);
        f2 P1L = dpp2_shr(P1), P1R = dpp2_shl(P1);
        f2 OL  = dpp2_shr(vc), OR_ = dpp2_shl(vc);

        f2 vn;
        #pragma unroll
        for (int a = 0; a < LQ; ++a) {
            // taps: dy=0 -> P0, dy=1 -> vc, dy=2 -> P1; cols L/C/R
            f2 acc = qr[a];
            acc = pk_fma_b0(P0L, wv2[a][0], acc);  // w0
            acc = pk_fma_b1(P0,  wv2[a][0], acc);  // w1
            acc = pk_fma_b0(P0R, wv2[a][1], acc);  // w2
            acc = pk_fma_b1(OL,  wv2[a][1], acc);  // w3
            acc = pk_fma_b0(vc,  wv2[a][2], acc);  // w4
            acc = pk_fma_b1(OR_, wv2[a][2], acc);  // w5
            acc = pk_fma_b0(P1L, wv2[a][3], acc);  // w6
            acc = pk_fma_b1(P1,  wv2[a][3], acc);  // w7
            acc = pk_fma_b0(P1R, wv2[a][4], acc);  // w8
            vn = (a == 0) ? acc : __builtin_elementwise_max(vn, acc);
        }
        vc = vn;
    }

    // ---- write out: lane l -> column l, rows base+2w, base+2w+1 ----
    float* ob = out + (size_t)img*HW*HW + (size_t)(base + 2*w)*HW + l;
    ob[0]  = vc.x;
    ob[HW] = vc.y;
}

extern "C" void kernel_launch(void* const* d_in, const int* in_sizes, int n_in,
                              void* d_out, int out_size, void* d_ws, size_t ws_size,
                              hipStream_t stream) {
    const float* X   = (const float*)d_in[0];
    const float* h_w = (const float*)d_in[1];
    const float* h_b = (const float*)d_in[2];
    const float* r_w = (const float*)d_in[3];
    const float* q_w = (const float*)d_in[4];
    const float* w   = (const float*)d_in[5];
    const int*   k   = (const int*)d_in[6];
    float* out = (float*)d_out;
    (void)d_ws; (void)ws_size;

    // reset halo seq tags each launch (graph-capturable)
    static void* haloPtr = nullptr;
    if (!haloPtr) hipGetSymbolAddress(&haloPtr, HIP_SYMBOL(g_halo));
    hipMemsetAsync(haloPtr, 0, sizeof(unsigned long long)*2*2*128*64, stream);

    vin_main<<<256, 1024, 0, stream>>>(X, h_w, h_b, r_w, q_w, w, k, out);
}